// Round 7
// baseline (150.910 us; speedup 1.0000x reference)
//
#include <hip/hip_runtime.h>
#include <hip/hip_bf16.h>

#define L2E  1.4426950408889634f
#define LN2f 0.6931471805599453f

typedef __attribute__((ext_vector_type(4))) float f32x4;
typedef __attribute__((ext_vector_type(4))) short s16x4;

#if __has_builtin(__builtin_amdgcn_mfma_f32_16x16x16bf16_1k)
__device__ __forceinline__ f32x4 mfma16(s16x4 a, s16x4 b) {
  f32x4 z = {0.f, 0.f, 0.f, 0.f};
  return __builtin_amdgcn_mfma_f32_16x16x16bf16_1k(a, b, z, 0, 0, 0);
}
#else
__device__ __forceinline__ f32x4 mfma16(s16x4 a, s16x4 b) {
  f32x4 d = {0.f, 0.f, 0.f, 0.f};
  asm volatile("s_nop 1\n\t"
               "v_mfma_f32_16x16x16_bf16 %0, %1, %2, %0\n\t"
               "s_nop 7\n\ts_nop 7"
               : "+v"(d) : "v"(a), "v"(b));
  return d;
}
#endif

__device__ __forceinline__ short f2bf(float f) {
  __hip_bfloat16 h = __float2bfloat16(f);
  return (short)__builtin_bit_cast(unsigned short, h);
}
__device__ __forceinline__ float rfl(float v) {
  return __builtin_bit_cast(float,
      __builtin_amdgcn_readfirstlane(__builtin_bit_cast(int, v)));
}

// fwd: v_t = mask_t ? diag(p_t)·W^T·v_{t-1} : v_{t-1},  t=1..255, v_0=exp(logit_0)
// bwd (w = p∘u): w_{t-1} = mask_t ? diag(p_{t-1})·W·w_t : diag(p_{t-1}/p_t)·w_t,
//                t=511..256, w_511 = p_511.  All via one 16x16x16 bf16 MFMA/step:
// state = B col 0; D layout == B layout (col=lane&15, k=(lane>>4)*4+reg) so the
// chain closes lane-locally. Rows/cols >= 15 stay exactly 0. Renorm every 4 by
// readfirstlane(d[0]) (state row 0; spread bounded by logit range, stays f32-safe).
template<bool BWD>
__device__ __forceinline__ void scan_mfma(
    const float* __restrict__ ep,     // logits + seq*7680
    const int*   __restrict__ ys,     // LDS labels for this seq (512)
    const float (&Wf)[4], const float (&If)[4], const s16x4 Ibf,
    int r, int jj, int g4, int lane,
    float* __restrict__ comb16, float* __restrict__ aux2)  // aux2: [0]=eacc
{
  const int jm = (r < 15) ? r : 255;
  const bool isCol0 = (r == 0);

  // ---- state init ----
  const float* e0 = BWD ? (ep + 511 * 15) : ep;
  float dv[4];
  #pragma unroll
  for (int q = 0; q < 4; ++q) {
    const int rowq = g4 * 4 + q;
    const float ev = e0[(rowq < 15) ? rowq : 14];
    dv[q] = (isCol0 && rowq < 15) ? ev : 0.0f;      // log units
  }
  const float base = rfl(dv[0]);                    // e_{t0}[0], wave-uniform
  float M = base * L2E;
  s16x4 b16;
  #pragma unroll
  for (int q = 0; q < 4; ++q) {
    const int rowq = g4 * 4 + q;
    const float x = (isCol0 && rowq < 15) ? exp2f((dv[q] - base) * L2E) : 0.0f;
    dv[q] = x;
    b16[q] = f2bf(x);
  }

  // ---- prefetch rings (1 emit + 1 label per step) ----
  const float* erow = ep + jj;                      // row-clamped lane stream
  float ering[8]; int ybuf[8];
  float eacc, ecur = 0.f, pcur = 1.f;
  const float* pe; const int* py;
  if (!BWD) {
    #pragma unroll
    for (int i = 0; i < 8; ++i) { ering[i] = erow[(1 + i) * 15]; ybuf[i] = ys[1 + i]; }
    pe = erow + 9 * 15;  py = ys + 9;
    const int y0 = ys[0];
    eacc = (y0 == jm) ? erow[0] : 0.f;
  } else {
    #pragma unroll
    for (int i = 0; i < 8; ++i) { ering[i] = erow[(510 - i) * 15]; ybuf[i] = ys[511 - i]; }
    pe = erow + 502 * 15;  py = ys + 503;
    ecur = erow[511 * 15];                          // e_511[r]
    pcur = exp2f(ecur * L2E);
    eacc = 0.f;
  }

  f32x4 d;

  // ---- one step (ring slot kk). RN: renorm this step ----
#define STEP(kk, RN)                                                        \
  do {                                                                      \
    const float ev_ = ering[kk]; const int yv_ = ybuf[kk];                  \
    ering[kk] = *pe; ybuf[kk] = *py;                                        \
    if (!BWD) { pe += 15; py += 1; } else { pe -= 15; py -= 1; }            \
    const bool mk_ = (yv_ != 15);                                           \
    const float pn_ = exp2f(ev_ * L2E);                                     \
    s16x4 a16_;                                                             \
    if (!BWD) {                                                             \
      a16_[0] = f2bf(pn_ * Wf[0]); a16_[1] = f2bf(pn_ * Wf[1]);             \
      a16_[2] = f2bf(pn_ * Wf[2]); a16_[3] = f2bf(pn_ * Wf[3]);             \
      if (!mk_) a16_ = Ibf;                                                 \
      eacc += (yv_ == jm) ? ev_ : 0.f;                                      \
    } else {                                                                \
      const float rr_ = pn_ * __builtin_amdgcn_rcpf(pcur);                  \
      a16_[0] = f2bf(mk_ ? pn_ * Wf[0] : rr_ * If[0]);                      \
      a16_[1] = f2bf(mk_ ? pn_ * Wf[1] : rr_ * If[1]);                      \
      a16_[2] = f2bf(mk_ ? pn_ * Wf[2] : rr_ * If[2]);                      \
      a16_[3] = f2bf(mk_ ? pn_ * Wf[3] : rr_ * If[3]);                      \
      eacc += (yv_ == jm) ? ecur : 0.f;                                     \
      ecur = ev_; pcur = pn_;                                               \
    }                                                                       \
    d = mfma16(a16_, b16);                                                  \
    if (RN) {                                                               \
      const float m_ = rfl(d[0]);                                           \
      M += log2f(m_);                                                       \
      const float iv_ = __builtin_amdgcn_rcpf(m_);                          \
      d[0] *= iv_; d[1] *= iv_; d[2] *= iv_; d[3] *= iv_;                   \
    }                                                                       \
    b16[0] = f2bf(d[0]); b16[1] = f2bf(d[1]);                               \
    b16[2] = f2bf(d[2]); b16[3] = f2bf(d[3]);                               \
  } while (0)

  if (!BWD) {
    for (int sb = 0; sb < 31; ++sb) {        // t = 1..248
      STEP(0, 0); STEP(1, 0); STEP(2, 0); STEP(3, 1);
      STEP(4, 0); STEP(5, 0); STEP(6, 0); STEP(7, 1);
    }
    STEP(0, 0); STEP(1, 0); STEP(2, 0); STEP(3, 1);   // t = 249..255
    STEP(4, 0); STEP(5, 0); STEP(6, 0);
  } else {
    for (int sb = 0; sb < 32; ++sb) {        // t = 511..256
      STEP(0, 0); STEP(1, 0); STEP(2, 0); STEP(3, 1);
      STEP(4, 0); STEP(5, 0); STEP(6, 0); STEP(7, 1);
    }
  }
#undef STEP

  // ---- write out: log2 state (col-0 lanes) + emission partial ----
  if (isCol0) {
    #pragma unroll
    for (int q = 0; q < 4; ++q) {
      const float x = d[q];
      comb16[g4 * 4 + q] = (x > 0.f) ? (M + log2f(x)) : -1.0e30f;
    }
  }
  eacc += __shfl_xor(eacc, 1, 16);
  eacc += __shfl_xor(eacc, 2, 16);
  eacc += __shfl_xor(eacc, 4, 16);
  eacc += __shfl_xor(eacc, 8, 16);
  if (lane == 0) aux2[0] = eacc;
}

__global__ __launch_bounds__(256, 8)
void crf_mfma2(const float* __restrict__ logits, const int* __restrict__ yg,
               const float* __restrict__ trans, float* __restrict__ out) {
  __shared__ float Tl[240];
  __shared__ int   yl[1024];
  __shared__ float comb[2][2][16];
  __shared__ float emS[2][2];
  __shared__ float transS[2];
  __shared__ float blks[2];

  const int tid = threadIdx.x;
  if (tid < 225) Tl[tid] = trans[tid];
  if (tid < 2) transS[tid] = 0.f;
  ((int4*)yl)[tid] = ((const int4*)(yg + (size_t)blockIdx.x * 1024))[tid];
  __syncthreads();

  // ---- transition part of the path score (LDS-only) ----
  {
    const int q = tid >> 7, l = tid & 127;
    const int* ysq = yl + q * 512;
    float acc = 0.f;
    #pragma unroll
    for (int m = 0; m < 4; ++m) {
      const int t = 1 + l + 128 * m;
      if (t < 512) {
        const int yc = ysq[t], yp = ysq[t - 1];
        if (yc < 15 && yp < 15) acc += Tl[yp * 15 + yc];
      }
    }
    #pragma unroll
    for (int k = 1; k < 64; k <<= 1) acc += __shfl_xor(acc, k, 64);
    if ((tid & 63) == 0) atomicAdd(&transS[q], acc);
  }

  // ---- wave -> (sequence, direction); full wave per chain ----
  const int wave = tid >> 6, lane = tid & 63;
  const int sl = wave >> 1;
  const bool isBwd = (wave & 1) != 0;
  const int seq = blockIdx.x * 2 + sl;
  const int r  = lane & 15;                 // A-row / B-col index
  const int jj = (r < 15) ? r : 14;         // clamped address row
  const int g4 = lane >> 4;                 // k/row block

  // A static parts. fwd: A[r][c] = p_r * exp2(T[c][r]*L2E); bwd: exp2(T[r][c]*L2E).
  float Wf[4], If[4];
  s16x4 Ibf;
  #pragma unroll
  for (int q = 0; q < 4; ++q) {
    const int c = g4 * 4 + q;
    const bool valid = (r < 15) && (c < 15);
    const int idx = isBwd ? (r * 15 + c) : (c * 15 + r);
    Wf[q] = valid ? exp2f(Tl[valid ? idx : 0] * L2E) : 0.f;
    If[q] = (r == c) ? 1.f : 0.f;
    Ibf[q] = f2bf(If[q]);
  }
  #pragma unroll
  for (int q = 0; q < 4; ++q) asm volatile("" : "+v"(Wf[q]));  // no remat (R5 lesson)

  const float* ep = logits + (size_t)seq * 7680;
  const int* ys = yl + sl * 512;
  const int dir = isBwd ? 1 : 0;

  if (isBwd) scan_mfma<true >(ep, ys, Wf, If, Ibf, r, jj, g4, lane,
                              &comb[sl][1][0], &emS[sl][1]);
  else       scan_mfma<false>(ep, ys, Wf, If, Ibf, r, jj, g4, lane,
                              &comb[sl][0][0], &emS[sl][0]);
  (void)dir;

  __syncthreads();

  // ---- combine: logZ = lse_r( log2 a_255[r] + log2 w_255[r] - e255[r]*L2E ) ----
  if (tid < 2) {
    const float* e255 = logits + (size_t)(blockIdx.x * 2 + tid) * 7680 + 255 * 15;
    float s[15]; float mx = -3.0e38f;
    #pragma unroll
    for (int i = 0; i < 15; ++i) {
      s[i] = comb[tid][0][i] + comb[tid][1][i] - e255[i] * L2E;
      mx = fmaxf(mx, s[i]);
    }
    float sum = 0.f;
    #pragma unroll
    for (int i = 0; i < 15; ++i) sum += exp2f(s[i] - mx);
    const float logZ = (mx + log2f(sum)) * LN2f;
    const float path = emS[tid][0] + emS[tid][1] + transS[tid];
    float nll = logZ - path;
    nll = fminf(fmaxf(nll, 0.f), 1000000.f);
    blks[tid] = nll;
  }
  __syncthreads();
  if (tid == 0) atomicAdd(out, (blks[0] + blks[1]) * (1.0f / 4096.0f));
}

extern "C" void kernel_launch(void* const* d_in, const int* in_sizes, int n_in,
                              void* d_out, int out_size, void* d_ws, size_t ws_size,
                              hipStream_t stream) {
  const float* logits = (const float*)d_in[0];   // (4096, 512, 15) f32
  const int*   y      = (const int*)d_in[1];     // (4096, 512) i32
  const float* trans  = (const float*)d_in[2];   // (15, 15) f32
  float* out = (float*)d_out;

  hipMemsetAsync(out, 0, sizeof(float), stream);

  const int B = in_sizes[1] / 512;               // 4096
  crf_mfma2<<<dim3(B / 2), dim3(256), 0, stream>>>(logits, y, trans, out);
}

// Round 8
// 63.486 us; speedup vs baseline: 2.3770x; 2.3770x over previous
//
#include <hip/hip_runtime.h>

#define L2E  1.4426950408889634f
#define LN2f 0.6931471805599453f

template<int CTRL>
__device__ __forceinline__ float dppf(float x) {
  int r = __builtin_amdgcn_update_dpp(0, __builtin_bit_cast(int, x), CTRL, 0xF, 0xF, true);
  return __builtin_bit_cast(float, r);
}
template<int CTRL>
__device__ __forceinline__ int dppi(int x) {
  return __builtin_amdgcn_update_dpp(0, x, CTRL, 0xF, 0xF, true);
}

// max over the 16-lane group via DPP butterfly (ctrl set verified R2/R4/R5, absmax 0)
__device__ __forceinline__ float bflymax16(float x) {
  x = fmaxf(x, dppf<0xB1>(x));    // lane^1
  x = fmaxf(x, dppf<0x4E>(x));    // lane^2
  x = fmaxf(x, dppf<0x141>(x));   // lane^7
  x = fmaxf(x, dppf<0x140>(x));   // lane^15
  return x;
}

// Fused rotate-and-dot (verified R4/R5): tot_j = sum_r rot_r(shv)_j * Wror[r]_j
#define DOT(shv, tot) {                                   \
    float t0_ = (shv) * Wror[0], t1_ = 0.f, t2_ = 0.f, t3_ = 0.f; \
    t1_ = fmaf(dppf<0x121>(shv), Wror[1],  t1_);          \
    t2_ = fmaf(dppf<0x122>(shv), Wror[2],  t2_);          \
    t3_ = fmaf(dppf<0x123>(shv), Wror[3],  t3_);          \
    t0_ = fmaf(dppf<0x124>(shv), Wror[4],  t0_);          \
    t1_ = fmaf(dppf<0x125>(shv), Wror[5],  t1_);          \
    t2_ = fmaf(dppf<0x126>(shv), Wror[6],  t2_);          \
    t3_ = fmaf(dppf<0x127>(shv), Wror[7],  t3_);          \
    t0_ = fmaf(dppf<0x128>(shv), Wror[8],  t0_);          \
    t1_ = fmaf(dppf<0x129>(shv), Wror[9],  t1_);          \
    t2_ = fmaf(dppf<0x12A>(shv), Wror[10], t2_);          \
    t3_ = fmaf(dppf<0x12B>(shv), Wror[11], t3_);          \
    t0_ = fmaf(dppf<0x12C>(shv), Wror[12], t0_);          \
    t1_ = fmaf(dppf<0x12D>(shv), Wror[13], t1_);          \
    t2_ = fmaf(dppf<0x12E>(shv), Wror[14], t2_);          \
    t3_ = fmaf(dppf<0x12F>(shv), Wror[15], t3_);          \
    tot = (t0_ + t1_) + (t2_ + t3_); }

// One fwd step (ring slot kk): v_t = mask ? diag(p_t)W^T v : v
#define STEPF(kk, RN, REFILL)                                         \
  do {                                                                \
    const float emit = ebuf[kk]; const int yi = ybuf[kk];             \
    if (REFILL) {                                                     \
      ebuf[kk] = *(const float*)(lb + eoff); eoff += 60;              \
      ybuf[kk] = *(const int*)(yb + yoff); yoff += 4;                 \
    }                                                                 \
    const float p = exp2f(emit * L2E);                                \
    float tot; DOT(own, tot);                                         \
    const float cand = tot * p;                                       \
    own = (yi != 15) ? cand : own;                                    \
    eacc += (yi == jm) ? emit : 0.f;                                  \
    if (RN) { const float m = bflymax16(own);                         \
      own *= __builtin_amdgcn_rcpf(m); M += log2f(m); }               \
  } while (0)

// One bwd step: u_{t-1} = mask_t ? W (p_t ∘ u_t) : u_t
#define STEPB(kk, RN, REFILL)                                         \
  do {                                                                \
    const float emit = ebuf[kk]; const int yi = ybuf[kk];             \
    if (REFILL) {                                                     \
      ebuf[kk] = *(const float*)(lb + eoff); eoff -= 60;              \
      ybuf[kk] = *(const int*)(yb + yoff); yoff -= 4;                 \
    }                                                                 \
    const float p = exp2f(emit * L2E);                                \
    const float share = own * p;                                      \
    float tot; DOT(share, tot);                                       \
    own = (yi != 15) ? tot : own;                                     \
    eacc += (yi == jm) ? emit : 0.f;                                  \
    if (RN) { const float m = bflymax16(own);                         \
      own *= __builtin_amdgcn_rcpf(m); M += log2f(m); }               \
  } while (0)

// Math identical to R5 (absmax 0). 16-deep global prefetch rings, no LDS in
// the loop. Refill ranges: fwd reads t=17..256, bwd t=495..256 -- in-bounds.
template<bool BWD>
__device__ __forceinline__ void scan(const char* __restrict__ lb,  // logits + seq*30720 + jj*4
                                     const char* __restrict__ yb,  // yg + seq*2048
                                     const float (&Wror)[16],
                                     int j, int jm,
                                     float& ownO, float& MO, float& eaccO) {
  float own, M, eacc;
  float ebuf[16]; int ybuf[16];
  int eoff, yoff;
  if (!BWD) {
    const float a0 = *(const float*)lb;            // t=0, own tag row
    const int y0 = *(const int*)yb;
    eacc = (y0 == jm) ? a0 : 0.f;
    const float A = (j < 15) ? a0 * L2E : -1.0e30f;
    const float M0 = bflymax16(A);
    own = exp2f(A - M0);
    M = M0;
    #pragma unroll
    for (int i = 0; i < 16; ++i) {
      ebuf[i] = *(const float*)(lb + (1 + i) * 60);
      ybuf[i] = *(const int*)(yb + (1 + i) * 4);
    }
    eoff = 17 * 60; yoff = 17 * 4;
  } else {
    eacc = 0.f;
    own = (j < 15) ? 1.f : 0.f;
    M = 0.f;
    #pragma unroll
    for (int i = 0; i < 16; ++i) {
      ebuf[i] = *(const float*)(lb + (511 - i) * 60);
      ybuf[i] = *(const int*)(yb + (511 - i) * 4);
    }
    eoff = 495 * 60; yoff = 495 * 4;
  }

  if (!BWD) {
    for (int sb = 0; sb < 15; ++sb) {            // t = 1..240
      STEPF(0,0,1);  STEPF(1,0,1);  STEPF(2,0,1);  STEPF(3,0,1);
      STEPF(4,0,1);  STEPF(5,0,1);  STEPF(6,0,1);  STEPF(7,1,1);
      STEPF(8,0,1);  STEPF(9,0,1);  STEPF(10,0,1); STEPF(11,0,1);
      STEPF(12,0,1); STEPF(13,0,1); STEPF(14,0,1); STEPF(15,1,1);
    }
    // tail t = 241..255 (15 steps, no refill; renorm mid-tail keeps f32 safe)
    STEPF(0,0,0);  STEPF(1,0,0);  STEPF(2,0,0);  STEPF(3,0,0);
    STEPF(4,0,0);  STEPF(5,0,0);  STEPF(6,0,0);  STEPF(7,1,0);
    STEPF(8,0,0);  STEPF(9,0,0);  STEPF(10,0,0); STEPF(11,0,0);
    STEPF(12,0,0); STEPF(13,0,0); STEPF(14,0,0);
  } else {
    for (int sb = 0; sb < 15; ++sb) {            // t = 511..272
      STEPB(0,0,1);  STEPB(1,0,1);  STEPB(2,0,1);  STEPB(3,0,1);
      STEPB(4,0,1);  STEPB(5,0,1);  STEPB(6,0,1);  STEPB(7,1,1);
      STEPB(8,0,1);  STEPB(9,0,1);  STEPB(10,0,1); STEPB(11,0,1);
      STEPB(12,0,1); STEPB(13,0,1); STEPB(14,0,1); STEPB(15,1,1);
    }
    // tail t = 271..256 (16 steps, no refill)
    STEPB(0,0,0);  STEPB(1,0,0);  STEPB(2,0,0);  STEPB(3,0,0);
    STEPB(4,0,0);  STEPB(5,0,0);  STEPB(6,0,0);  STEPB(7,1,0);
    STEPB(8,0,0);  STEPB(9,0,0);  STEPB(10,0,0); STEPB(11,0,0);
    STEPB(12,0,0); STEPB(13,0,0); STEPB(14,0,0); STEPB(15,0,0);
  }
  ownO = own; MO = M; eaccO = eacc;
}

__global__ __launch_bounds__(256, 2)
void crf_g(const float* __restrict__ logits, const int* __restrict__ yg,
           const float* __restrict__ trans, float* __restrict__ out) {
  __shared__ float Tl[240];
  __shared__ float comb[8][2][16];
  __shared__ float pathE[8][2];
  __shared__ float transS[8];
  __shared__ float blks[8];

  const int tid = threadIdx.x;
  if (tid < 225) Tl[tid] = trans[tid];
  __syncthreads();

  const char* yb0 = (const char*)yg + (size_t)blockIdx.x * 8 * 2048;

  // ---- transition part of path score (global y, coalesced; one-time) ----
  {
    const int q = tid >> 5, l32 = tid & 31;
    const int* ys = (const int*)(yb0 + q * 2048);
    float acc = 0.f;
    #pragma unroll
    for (int m = 0; m < 16; ++m) {
      const int t = 1 + l32 + 32 * m;
      if (t < 512) {
        const int yc = ys[t], yp = ys[t - 1];
        if (yc < 15 && yp < 15) acc += Tl[yp * 15 + yc];
      }
    }
    #pragma unroll
    for (int k = 1; k < 32; k <<= 1) acc += __shfl_xor(acc, k, 32);
    if (l32 == 0) transS[q] = acc;
  }

  // ---- chain setup: 16 lanes/chain, 4 chains/wave; whole wave fwd or bwd ----
  const int wave = tid >> 6, lane = tid & 63;
  const int j = lane & 15;
  const int sLoc = (wave >> 1) * 4 + (lane >> 4);   // 0..7
  const bool isFwd = (wave & 1) == 0;
  const int seq = blockIdx.x * 8 + sLoc;
  const int jj = (j < 15) ? j : 14;
  const int jm = (j < 15) ? j : 255;
  const char* lb = (const char*)logits + (size_t)seq * 30720 + jj * 4;
  const char* yb = yb0 + sLoc * 2048;

  // Wror[r][j] = exp(T[src][j]) (fwd) / exp(T[j][src]) (bwd); src derived by
  // applying the SAME DPP op to the lane index (direction-proof; R4/R5-verified).
  float Wror[16];
  Wror[0] = (j < 15) ? exp2f(Tl[j * 16] * L2E) : 0.f;
#define SETW(R) { const int s_ = dppi<0x120 + (R)>(j);                  \
    const bool v_ = (j < 15) && (s_ < 15);                              \
    const int ix_ = isFwd ? s_ * 15 + j : j * 15 + s_;                  \
    Wror[R] = v_ ? exp2f(Tl[v_ ? ix_ : 0] * L2E) : 0.f; }
  SETW(1)  SETW(2)  SETW(3)  SETW(4)  SETW(5)
  SETW(6)  SETW(7)  SETW(8)  SETW(9)  SETW(10)
  SETW(11) SETW(12) SETW(13) SETW(14) SETW(15)
#undef SETW
  // Pin Wror in VGPRs (R5 win: prevents in-loop rematerialization)
  #pragma unroll
  for (int r = 0; r < 16; ++r) asm volatile("" : "+v"(Wror[r]));

  float own, M, eacc;
  if (isFwd) scan<false>(lb, yb, Wror, j, jm, own, M, eacc);
  else       scan<true >(lb, yb, Wror, j, jm, own, M, eacc);

  const int dir = isFwd ? 0 : 1;
  if (j < 15) comb[sLoc][dir][j] = M + log2f(own);
  #pragma unroll
  for (int k = 1; k < 16; k <<= 1) eacc += __shfl_xor(eacc, k, 16);
  if (j == 0) pathE[sLoc][dir] = eacc;

  __syncthreads();

  // ---- per-sequence combine: logZ = lse_i(log v_255[i] + log u_255[i]) ----
  if (tid < 8) {
    float mx = -3.0e38f; float s[15];
    #pragma unroll
    for (int i = 0; i < 15; ++i) {
      s[i] = comb[tid][0][i] + comb[tid][1][i];
      mx = fmaxf(mx, s[i]);
    }
    float sum = 0.f;
    #pragma unroll
    for (int i = 0; i < 15; ++i) sum += exp2f(s[i] - mx);
    const float logZ = (mx + log2f(sum)) * LN2f;
    const float path = pathE[tid][0] + pathE[tid][1] + transS[tid];
    float nll = logZ - path;
    nll = fminf(fmaxf(nll, 0.f), 1000000.f);
    blks[tid] = nll;
  }
  __syncthreads();
  if (tid == 0) {
    const float tot = (blks[0] + blks[1]) + (blks[2] + blks[3]) +
                      (blks[4] + blks[5]) + (blks[6] + blks[7]);
    atomicAdd(out, tot * (1.0f / 4096.0f));
  }
}

extern "C" void kernel_launch(void* const* d_in, const int* in_sizes, int n_in,
                              void* d_out, int out_size, void* d_ws, size_t ws_size,
                              hipStream_t stream) {
  const float* logits = (const float*)d_in[0];   // (4096, 512, 15) f32
  const int*   y      = (const int*)d_in[1];     // (4096, 512) i32
  const float* trans  = (const float*)d_in[2];   // (15, 15) f32
  float* out = (float*)d_out;

  hipMemsetAsync(out, 0, sizeof(float), stream);

  const int B = in_sizes[1] / 512;               // 4096
  crf_g<<<dim3(B / 8), dim3(256), 0, stream>>>(logits, y, trans, out);
}

// Round 9
// 61.336 us; speedup vs baseline: 2.4604x; 1.0351x over previous
//
#include <hip/hip_runtime.h>

#define L2E  1.4426950408889634f
#define LN2f 0.6931471805599453f

template<int CTRL>
__device__ __forceinline__ float dppf(float x) {
  int r = __builtin_amdgcn_update_dpp(0, __builtin_bit_cast(int, x), CTRL, 0xF, 0xF, true);
  return __builtin_bit_cast(float, r);
}
template<int CTRL>
__device__ __forceinline__ int dppi(int x) {
  return __builtin_amdgcn_update_dpp(0, x, CTRL, 0xF, 0xF, true);
}

// max over the 16-lane group via DPP butterfly (verified R2/R4/R5/R8, absmax 0)
__device__ __forceinline__ float bflymax16(float x) {
  x = fmaxf(x, dppf<0xB1>(x));    // lane^1
  x = fmaxf(x, dppf<0x4E>(x));    // lane^2
  x = fmaxf(x, dppf<0x141>(x));   // lane^7
  x = fmaxf(x, dppf<0x140>(x));   // lane^15
  return x;
}

// Fused rotate-and-dot (verified R4/R5/R8): tot_j = sum_r rot_r(shv)_j * Wror[r]_j
#define DOT(shv, tot) {                                   \
    float t0_ = (shv) * Wror[0], t1_ = 0.f, t2_ = 0.f, t3_ = 0.f; \
    t1_ = fmaf(dppf<0x121>(shv), Wror[1],  t1_);          \
    t2_ = fmaf(dppf<0x122>(shv), Wror[2],  t2_);          \
    t3_ = fmaf(dppf<0x123>(shv), Wror[3],  t3_);          \
    t0_ = fmaf(dppf<0x124>(shv), Wror[4],  t0_);          \
    t1_ = fmaf(dppf<0x125>(shv), Wror[5],  t1_);          \
    t2_ = fmaf(dppf<0x126>(shv), Wror[6],  t2_);          \
    t3_ = fmaf(dppf<0x127>(shv), Wror[7],  t3_);          \
    t0_ = fmaf(dppf<0x128>(shv), Wror[8],  t0_);          \
    t1_ = fmaf(dppf<0x129>(shv), Wror[9],  t1_);          \
    t2_ = fmaf(dppf<0x12A>(shv), Wror[10], t2_);          \
    t3_ = fmaf(dppf<0x12B>(shv), Wror[11], t3_);          \
    t0_ = fmaf(dppf<0x12C>(shv), Wror[12], t0_);          \
    t1_ = fmaf(dppf<0x12D>(shv), Wror[13], t1_);          \
    t2_ = fmaf(dppf<0x12E>(shv), Wror[14], t2_);          \
    t3_ = fmaf(dppf<0x12F>(shv), Wror[15], t3_);          \
    tot = (t0_ + t1_) + (t2_ + t3_); }

// counted wait + scheduling fence (rule 18: sched_barrier right after asm waitcnt)
#define VWAIT(N) do { asm volatile("s_waitcnt vmcnt(" #N ")" ::: "memory"); \
                      __builtin_amdgcn_sched_barrier(0); } while (0)
#define SBAR()   __builtin_amdgcn_sched_barrier(0)

// fwd step: v_t = mask_t ? diag(p_t)·W^T·v : v   (math verified R5/R8)
#define FSTEP(emit, yi, RN) do {                                      \
    const float e_ = (emit); const int yi_ = (yi);                    \
    const float p_ = exp2f(e_ * L2E);                                 \
    float tot_; DOT(own, tot_);                                       \
    const float cand_ = tot_ * p_;                                    \
    own = (yi_ != 15) ? cand_ : own;                                  \
    eacc += (yi_ == jm) ? e_ : 0.f;                                   \
    if (RN) { const float m_ = bflymax16(own);                        \
      own *= __builtin_amdgcn_rcpf(m_); M += log2f(m_); }             \
  } while (0)

// bwd step: u_{t-1} = mask_t ? W·(p_t ∘ u_t) : u_t
#define BSTEP(emit, yi, RN) do {                                      \
    const float e_ = (emit); const int yi_ = (yi);                    \
    const float p_ = exp2f(e_ * L2E);                                 \
    const float sh_ = own * p_;                                       \
    float tot_; DOT(sh_, tot_);                                       \
    own = (yi_ != 15) ? tot_ : own;                                   \
    eacc += (yi_ == jm) ? e_ : 0.f;                                   \
    if (RN) { const float m_ = bflymax16(own);                        \
      own *= __builtin_amdgcn_rcpf(m_); M += log2f(m_); }             \
  } while (0)

// batch issue, fwd: 8 emits (stride +60B, imm offsets) + 2 int4 y loads
#define FISS(EB, Y0, Y1) do {                                         \
    EB[0] = *(const float*)(eub + evoff);                             \
    EB[1] = *(const float*)(eub + evoff + 60);                        \
    EB[2] = *(const float*)(eub + evoff + 120);                       \
    EB[3] = *(const float*)(eub + evoff + 180);                       \
    EB[4] = *(const float*)(eub + evoff + 240);                       \
    EB[5] = *(const float*)(eub + evoff + 300);                       \
    EB[6] = *(const float*)(eub + evoff + 360);                       \
    EB[7] = *(const float*)(eub + evoff + 420);                       \
    Y0 = *(const int4*)(yub + yvoff);                                 \
    Y1 = *(const int4*)(yub + yvoff + 16);                            \
    evoff += 480; yvoff += 32;                                        \
  } while (0)

// batch issue, bwd: descending t; evoff at t_hi, yvoff at (t_hi-7)*4
#define BISS(EB, Y0, Y1) do {                                         \
    EB[0] = *(const float*)(eub + evoff);                             \
    EB[1] = *(const float*)(eub + evoff - 60);                        \
    EB[2] = *(const float*)(eub + evoff - 120);                       \
    EB[3] = *(const float*)(eub + evoff - 180);                       \
    EB[4] = *(const float*)(eub + evoff - 240);                       \
    EB[5] = *(const float*)(eub + evoff - 300);                       \
    EB[6] = *(const float*)(eub + evoff - 360);                       \
    EB[7] = *(const float*)(eub + evoff - 420);                       \
    Y0 = *(const int4*)(yub + yvoff);                                 \
    Y1 = *(const int4*)(yub + yvoff + 16);                            \
    evoff -= 480; yvoff -= 32;                                        \
  } while (0)

// batch consume (8 steps), renorm on last
#define FCONS(EB, Y0, Y1) do {                                        \
    FSTEP(EB[0], (Y0).x, 0); FSTEP(EB[1], (Y0).y, 0);                 \
    FSTEP(EB[2], (Y0).z, 0); FSTEP(EB[3], (Y0).w, 0);                 \
    FSTEP(EB[4], (Y1).x, 0); FSTEP(EB[5], (Y1).y, 0);                 \
    FSTEP(EB[6], (Y1).z, 0); FSTEP(EB[7], (Y1).w, 1);                 \
  } while (0)

#define BCONS(EB, Y0, Y1) do {                                        \
    BSTEP(EB[0], (Y1).w, 0); BSTEP(EB[1], (Y1).z, 0);                 \
    BSTEP(EB[2], (Y1).y, 0); BSTEP(EB[3], (Y1).x, 0);                 \
    BSTEP(EB[4], (Y0).w, 0); BSTEP(EB[5], (Y0).z, 0);                 \
    BSTEP(EB[6], (Y0).y, 0); BSTEP(EB[7], (Y0).x, 1);                 \
  } while (0)

__global__ __launch_bounds__(256, 2)
void crf_batch(const float* __restrict__ logits, const int* __restrict__ yg,
               const float* __restrict__ trans, float* __restrict__ out) {
  __shared__ float Tl[240];
  __shared__ float comb[8][2][16];
  __shared__ float pathE[8][2];
  __shared__ float transS[8];
  __shared__ float blks[8];

  const int tid = threadIdx.x;
  if (tid < 225) Tl[tid] = trans[tid];
  __syncthreads();

  // wave-uniform bases (SADDR form); per-lane work lives in 32-bit voffsets
  const char* eub = (const char*)logits + (size_t)blockIdx.x * (8 * 30720);
  const char* yub = (const char*)yg + (size_t)blockIdx.x * (8 * 2048);

  // ---- transition part of path score (global y, coalesced; one-time) ----
  {
    const int q = tid >> 5, l32 = tid & 31;
    const int* ys = (const int*)(yub + q * 2048);
    float acc = 0.f;
    #pragma unroll
    for (int m = 0; m < 16; ++m) {
      const int t = 1 + l32 + 32 * m;
      if (t < 512) {
        const int yc = ys[t], yp = ys[t - 1];
        if (yc < 15 && yp < 15) acc += Tl[yp * 15 + yc];
      }
    }
    #pragma unroll
    for (int k = 1; k < 32; k <<= 1) acc += __shfl_xor(acc, k, 32);
    if (l32 == 0) transS[q] = acc;
  }

  // ---- chain setup: 16 lanes/chain, 4 chains/wave; whole wave fwd or bwd ----
  const int wave = tid >> 6, lane = tid & 63;
  const int j = lane & 15;
  const int sLoc = (wave >> 1) * 4 + (lane >> 4);   // 0..7
  const bool isFwd = (wave & 1) == 0;
  const int jj = (j < 15) ? j : 14;
  const int jm = (j < 15) ? j : 255;
  const int sBase = sLoc * 30720;
  const int yBase = sLoc * 2048;

  // Wror (direction-proof construction, verified R4/R5/R8)
  float Wror[16];
  Wror[0] = (j < 15) ? exp2f(Tl[j * 16] * L2E) : 0.f;
#define SETW(R) { const int s_ = dppi<0x120 + (R)>(j);                  \
    const bool v_ = (j < 15) && (s_ < 15);                              \
    const int ix_ = isFwd ? s_ * 15 + j : j * 15 + s_;                  \
    Wror[R] = v_ ? exp2f(Tl[v_ ? ix_ : 0] * L2E) : 0.f; }
  SETW(1)  SETW(2)  SETW(3)  SETW(4)  SETW(5)
  SETW(6)  SETW(7)  SETW(8)  SETW(9)  SETW(10)
  SETW(11) SETW(12) SETW(13) SETW(14) SETW(15)
#undef SETW
  #pragma unroll
  for (int r = 0; r < 16; ++r) asm volatile("" : "+v"(Wror[r]));  // pin (R5 win)

  float own, M, eacc;
  float ebA[8], ebB[8];
  int4 yA0, yA1, yB0, yB1;

  if (isFwd) {
    // prologue: t=0..7 via plain loads (2 int4 for y)
    int evoff = sBase + jj * 4;           // t=0
    int yvoff = yBase;
    float e0[8];
    #pragma unroll
    for (int i = 0; i < 8; ++i) e0[i] = *(const float*)(eub + evoff + i * 60);
    const int4 yP0 = *(const int4*)(yub + yvoff);        // y0..y3
    const int4 yP1 = *(const int4*)(yub + yvoff + 16);   // y4..y7
    evoff += 480; yvoff += 32;                            // -> t=8
    FISS(ebA, yA0, yA1);   // b0: t=8..15
    FISS(ebB, yB0, yB1);   // b1: t=16..23
    SBAR();

    // init (t=0) + 7 prologue steps (t=1..7), renorm at t=7
    const float a0 = e0[0];
    eacc = (yP0.x == jm) ? a0 : 0.f;
    const float A = (j < 15) ? a0 * L2E : -1.0e30f;
    const float M0 = bflymax16(A);
    own = exp2f(A - M0);
    M = M0;
    FSTEP(e0[1], yP0.y, 0); FSTEP(e0[2], yP0.z, 0); FSTEP(e0[3], yP0.w, 0);
    FSTEP(e0[4], yP1.x, 0); FSTEP(e0[5], yP1.y, 0); FSTEP(e0[6], yP1.z, 0);
    FSTEP(e0[7], yP1.w, 1);

    // main: consume b0..b30 (t=8..255); double-buffered, counted vmcnt
    #pragma unroll 1
    for (int k = 0; k < 14; ++k) {
      VWAIT(10); FCONS(ebA, yA0, yA1); FISS(ebA, yA0, yA1); SBAR();
      VWAIT(10); FCONS(ebB, yB0, yB1); FISS(ebB, yB0, yB1); SBAR();
    }
    VWAIT(10); FCONS(ebA, yA0, yA1); FISS(ebA, yA0, yA1); SBAR();  // b28; issue b30
    VWAIT(10); FCONS(ebB, yB0, yB1);                               // b29
    VWAIT(0);  FCONS(ebA, yA0, yA1);                               // b30 (t=248..255)
  } else {
    // bwd: t=511..256 in 32 batches
    int evoff = sBase + jj * 4 + 511 * 60;   // t=511
    int yvoff = yBase + 504 * 4;             // (t_hi-7)*4
    own = (j < 15) ? 1.f : 0.f;
    M = 0.f; eacc = 0.f;
    BISS(ebA, yA0, yA1);   // b0: t=511..504
    BISS(ebB, yB0, yB1);   // b1: t=503..496
    SBAR();
    #pragma unroll 1
    for (int k = 0; k < 15; ++k) {
      VWAIT(10); BCONS(ebA, yA0, yA1); BISS(ebA, yA0, yA1); SBAR();
      VWAIT(10); BCONS(ebB, yB0, yB1); BISS(ebB, yB0, yB1); SBAR();
    }
    VWAIT(10); BCONS(ebA, yA0, yA1);   // b30 (t=271..264)
    VWAIT(0);  BCONS(ebB, yB0, yB1);   // b31 (t=263..256)
  }

  const int dir = isFwd ? 0 : 1;
  if (j < 15) comb[sLoc][dir][j] = M + log2f(own);
  #pragma unroll
  for (int k = 1; k < 16; k <<= 1) eacc += __shfl_xor(eacc, k, 16);
  if (j == 0) pathE[sLoc][dir] = eacc;

  __syncthreads();

  // ---- per-sequence combine: logZ = lse_i(log v_255[i] + log u_255[i]) ----
  if (tid < 8) {
    float mx = -3.0e38f; float s[15];
    #pragma unroll
    for (int i = 0; i < 15; ++i) {
      s[i] = comb[tid][0][i] + comb[tid][1][i];
      mx = fmaxf(mx, s[i]);
    }
    float sum = 0.f;
    #pragma unroll
    for (int i = 0; i < 15; ++i) sum += exp2f(s[i] - mx);
    const float logZ = (mx + log2f(sum)) * LN2f;
    const float path = pathE[tid][0] + pathE[tid][1] + transS[tid];
    float nll = logZ - path;
    nll = fminf(fmaxf(nll, 0.f), 1000000.f);
    blks[tid] = nll;
  }
  __syncthreads();
  if (tid == 0) {
    const float tot = (blks[0] + blks[1]) + (blks[2] + blks[3]) +
                      (blks[4] + blks[5]) + (blks[6] + blks[7]);
    atomicAdd(out, tot * (1.0f / 4096.0f));
  }
}

extern "C" void kernel_launch(void* const* d_in, const int* in_sizes, int n_in,
                              void* d_out, int out_size, void* d_ws, size_t ws_size,
                              hipStream_t stream) {
  const float* logits = (const float*)d_in[0];   // (4096, 512, 15) f32
  const int*   y      = (const int*)d_in[1];     // (4096, 512) i32
  const float* trans  = (const float*)d_in[2];   // (15, 15) f32
  float* out = (float*)d_out;

  hipMemsetAsync(out, 0, sizeof(float), stream);

  const int B = in_sizes[1] / 512;               // 4096
  crf_batch<<<dim3(B / 8), dim3(256), 0, stream>>>(logits, y, trans, out);
}